// Round 4
// baseline (342.811 us; speedup 1.0000x reference)
//
#include <hip/hip_runtime.h>
#include <hip/hip_bf16.h>

// ---------- common types ----------
typedef __attribute__((ext_vector_type(8))) short bf16x8;
typedef __attribute__((ext_vector_type(4))) float f32x4;

__device__ __forceinline__ ushort f2bf(float f) {
  unsigned int u = __float_as_uint(f);
  u += 0x7fffu + ((u >> 16) & 1u);   // RNE
  return (ushort)(u >> 16);
}

__device__ __forceinline__ void gl_lds16(const void* g, void* l) {
  __builtin_amdgcn_global_load_lds(
      (const __attribute__((address_space(1))) void*)g,
      (__attribute__((address_space(3))) void*)l, 16, 0, 0);
}

#define SB() __builtin_amdgcn_sched_barrier(0)

// ---------- weight convert+transpose: W[K][N] f32 -> Wt[N][K] bf16 ----------
__global__ __launch_bounds__(256) void transpose_w(
    const float* __restrict__ W, ushort* __restrict__ Wt, int K, int N) {
  __shared__ float tile[32][33];
  const int tx = threadIdx.x, ty = threadIdx.y;  // (32, 8)
  const int bx = blockIdx.x, by = blockIdx.y;
#pragma unroll
  for (int j = 0; j < 4; j++)
    tile[ty + j * 8][tx] = W[(size_t)(by * 32 + ty + j * 8) * N + bx * 32 + tx];
  __syncthreads();
#pragma unroll
  for (int j = 0; j < 4; j++)
    Wt[(size_t)(bx * 32 + ty + j * 8) * K + by * 32 + tx] =
        f2bf(tile[tx][ty + j * 8]);
}

// ---------- V transpose: qkv V-part -> vt[bh][d][n] bf16 ----------
__global__ __launch_bounds__(256) void transpose_v(
    const ushort* __restrict__ qkv, ushort* __restrict__ vt) {
  __shared__ ushort tile[32][33];
  const int tx = threadIdx.x, ty = threadIdx.y;  // (32, 8)
  const int n0 = blockIdx.x * 32;
  const int d0 = blockIdx.y * 32;
  const int bh = blockIdx.z;
  const int bidx = bh >> 4, h = bh & 15;
#pragma unroll
  for (int j = 0; j < 4; j++)
    tile[ty + j * 8][tx] =
        qkv[(size_t)(bidx * 1024 + n0 + ty + j * 8) * 3072 + 2048 + h * 64 +
            d0 + tx];
  __syncthreads();
#pragma unroll
  for (int j = 0; j < 4; j++)
    vt[(size_t)(bh * 64 + d0 + ty + j * 8) * 1024 + n0 + tx] =
        tile[tx][ty + j * 8];
}

// ---------- layernorm: f32 row(1024) -> bf16 ----------
__global__ __launch_bounds__(256) void ln_bf16(
    const float* __restrict__ x, const float* __restrict__ g,
    const float* __restrict__ b, ushort* __restrict__ out) {
  const int row = blockIdx.x;
  const int t = threadIdx.x;
  float4 v = ((const float4*)(x + (size_t)row * 1024))[t];
  float s = v.x + v.y + v.z + v.w;
  float ss = v.x * v.x + v.y * v.y + v.z * v.z + v.w * v.w;
#pragma unroll
  for (int msk = 1; msk < 64; msk <<= 1) {
    s += __shfl_xor(s, msk);
    ss += __shfl_xor(ss, msk);
  }
  __shared__ float red[8];
  const int wv = t >> 6, ln = t & 63;
  if (ln == 0) { red[wv * 2] = s; red[wv * 2 + 1] = ss; }
  __syncthreads();
  s = red[0] + red[2] + red[4] + red[6];
  ss = red[1] + red[3] + red[5] + red[7];
  const float mu = s * (1.0f / 1024.0f);
  const float var = ss * (1.0f / 1024.0f) - mu * mu;
  const float rstd = rsqrtf(var + 1e-5f);
  float4 gv = ((const float4*)g)[t];
  float4 bv = ((const float4*)b)[t];
  ushort4 o;
  o.x = f2bf((v.x - mu) * rstd * gv.x + bv.x);
  o.y = f2bf((v.y - mu) * rstd * gv.y + bv.y);
  o.z = f2bf((v.z - mu) * rstd * gv.z + bv.z);
  o.w = f2bf((v.w - mu) * rstd * gv.w + bv.w);
  ((ushort4*)(out + (size_t)row * 1024))[t] = o;
}

// ---------- 128^2 GEMM (kept for N=1024 shapes: proj, fc2) ----------
template <int EPI>
__global__ __launch_bounds__(256) void gemm_bt(
    const ushort* __restrict__ A, const ushort* __restrict__ Bt,
    const float* __restrict__ bias, const float* __restrict__ resid,
    void* __restrict__ outp, int M, int N, int K) {
  __shared__ ushort sA[128 * 32];
  __shared__ ushort sB[128 * 32];
  const int t = threadIdx.x;
  const int lane = t & 63, wv = t >> 6;
  const int lr = lane & 15, lc = lane >> 4;
  const int m0 = blockIdx.y * 128, n0 = blockIdx.x * 128;
  const int wr = (wv >> 1) * 64, wc = (wv & 1) * 64;
  const int ch = t & 3;

  f32x4 acc[4][4];
#pragma unroll
  for (int m = 0; m < 4; m++)
#pragma unroll
    for (int n = 0; n < 4; n++) acc[m][n] = (f32x4){0.f, 0.f, 0.f, 0.f};

  for (int k0 = 0; k0 < K; k0 += 32) {
    __syncthreads();
#pragma unroll
    for (int s = 0; s < 2; s++) {
      const int r2 = (s * 256 + t) >> 2;
      gl_lds16(A + (size_t)(m0 + r2) * K + k0 + ch * 8, sA + s * 2048 + wv * 512);
      gl_lds16(Bt + (size_t)(n0 + r2) * K + k0 + ch * 8, sB + s * 2048 + wv * 512);
    }
    __syncthreads();
    bf16x8 af[4], bfr[4];
#pragma unroll
    for (int m = 0; m < 4; m++)
      af[m] = *(const bf16x8*)&sA[(wr + m * 16 + lr) * 32 + lc * 8];
#pragma unroll
    for (int n = 0; n < 4; n++)
      bfr[n] = *(const bf16x8*)&sB[(wc + n * 16 + lr) * 32 + lc * 8];
#pragma unroll
    for (int m = 0; m < 4; m++)
#pragma unroll
      for (int n = 0; n < 4; n++)
        acc[m][n] = __builtin_amdgcn_mfma_f32_16x16x32_bf16(af[m], bfr[n],
                                                            acc[m][n], 0, 0, 0);
  }

#pragma unroll
  for (int m = 0; m < 4; m++) {
#pragma unroll
    for (int n = 0; n < 4; n++) {
      const int gr0 = m0 + wr + m * 16 + lc * 4;
      const int gc = n0 + wc + n * 16 + lr;
      const float bs = bias[gc];
#pragma unroll
      for (int r = 0; r < 4; r++) {
        const float v = acc[m][n][r] + bs;
        const int gr = gr0 + r;
        if (EPI == 0) {
          ((ushort*)outp)[(size_t)gr * N + gc] = f2bf(v);
        } else if (EPI == 1) {
          const float gg = 0.5f * v * (1.0f + erff(v * 0.70710678118654752f));
          ((ushort*)outp)[(size_t)gr * N + gc] = f2bf(gg);
        } else {
          ((float*)outp)[(size_t)gr * N + gc] =
              v + resid[(size_t)gr * N + gc];
        }
      }
    }
  }
}

// ---------- 256^2 8-phase GEMM (T2 swizzle + counted vmcnt + setprio) ----------
// C[M][N] = A[M][K] * Bt[N][K]^T + bias. EPI 0: ->bf16. EPI 1: GELU->bf16.
// 512 threads = 8 waves (2 Mx4 N), BK=64, 128KB LDS double-buffered.
template <int EPI>
__global__ __launch_bounds__(512, 2) void gemm256(
    const ushort* __restrict__ A, const ushort* __restrict__ Bt,
    const float* __restrict__ bias, void* __restrict__ outp,
    int M, int N, int K) {
  __shared__ ushort smem[65536];
  const int t = threadIdx.x;
  const int lane = t & 63, wid = t >> 6;
  const int lr = lane & 15, lc = lane >> 4;
  const int wr = wid >> 2, wc = wid & 3;
  const int m0 = blockIdx.y * 256, n0 = blockIdx.x * 256;
  const int nkt = K >> 6;

  // staging: chunk = 64 rows x 128B; lane t -> row t>>3, 16B-unit (t&7)
  // source col unit pre-swizzled: u' = (t&7) ^ ((row>>2)&3)
  const size_t lnoff =
      (size_t)(t >> 3) * (size_t)K + (size_t)(((t & 7) ^ ((t >> 5) & 3)) * 8);
  const int wvb = wid * 512;  // per-wave 1KB slice of each 8KB chunk
  const int swz = (lr >> 2) & 3;
  const int au8 = (lc ^ swz) * 8;          // swizzled ds_read unit (kk=0)
  const int arow = (wr * 128 + lr) * 64;   // + mf*1024
  const int brow = (wc * 64 + lr) * 64;    // + nf*1024

  f32x4 acc[8][4];
#pragma unroll
  for (int m = 0; m < 8; m++)
#pragma unroll
    for (int n = 0; n < 4; n++) acc[m][n] = (f32x4){0.f, 0.f, 0.f, 0.f};

  auto stA = [&](int bb, int c, int kt) {
    gl_lds16(A + (size_t)(m0 + c * 64) * K + (size_t)(kt * 64) + lnoff,
             &smem[bb * 16384 + c * 4096 + wvb]);
  };
  auto stB = [&](int bb, int c, int kt) {
    gl_lds16(Bt + (size_t)(n0 + c * 64) * K + (size_t)(kt * 64) + lnoff,
             &smem[32768 + bb * 16384 + c * 4096 + wvb]);
  };
  auto rdA = [&](int bb, int mf, int kk) {
    return *(const bf16x8*)&smem[bb * 16384 + arow + mf * 1024 + au8 + kk * 32];
  };
  auto rdB = [&](int bb, int nf, int kk) {
    return *(const bf16x8*)&smem[32768 + bb * 16384 + brow + nf * 1024 + au8 +
                                 kk * 32];
  };

  // prologue: stage K-tile 0 fully + tile 1's A chunks 0,2 (steady-state
  // phase-4 staging covers A0/A2 only for tiles >= 2), drain, barrier.
#pragma unroll
  for (int c = 0; c < 4; c++) stA(0, c, 0);
#pragma unroll
  for (int c = 0; c < 4; c++) stB(0, c, 0);
  if (nkt > 1) { stA(1, 0, 1); stA(1, 2, 1); }
  asm volatile("s_waitcnt vmcnt(0)" ::: "memory");
  SB(); __builtin_amdgcn_s_barrier(); SB();

  int b = 0;
  for (int k = 0; k < nkt; k++, b ^= 1) {
    const bool pf1 = (k + 1 < nkt);
    const bool pf2 = (k + 2 < nkt);
    bf16x8 Ar[4][2], Br[2][2];

    // ---- phase 1: A mh0 + B nh0 -> acc[0..3][0..1]; stage B01(k+1) ----
#pragma unroll
    for (int mf = 0; mf < 4; mf++) {
      Ar[mf][0] = rdA(b, mf, 0);
      Ar[mf][1] = rdA(b, mf, 1);
    }
    Br[0][0] = rdB(b, 0, 0); Br[0][1] = rdB(b, 0, 1);
    Br[1][0] = rdB(b, 1, 0); Br[1][1] = rdB(b, 1, 1);
    if (pf1) { stB(b ^ 1, 0, k + 1); stB(b ^ 1, 1, k + 1); }
    SB(); __builtin_amdgcn_s_barrier(); SB();
    __builtin_amdgcn_s_setprio(1);
#pragma unroll
    for (int mf = 0; mf < 4; mf++)
#pragma unroll
      for (int nf = 0; nf < 2; nf++) {
        acc[mf][nf] = __builtin_amdgcn_mfma_f32_16x16x32_bf16(
            Ar[mf][0], Br[nf][0], acc[mf][nf], 0, 0, 0);
        acc[mf][nf] = __builtin_amdgcn_mfma_f32_16x16x32_bf16(
            Ar[mf][1], Br[nf][1], acc[mf][nf], 0, 0, 0);
      }
    __builtin_amdgcn_s_setprio(0);
    if (pf2) asm volatile("s_waitcnt vmcnt(6)" ::: "memory");
    else     asm volatile("s_waitcnt vmcnt(0)" ::: "memory");
    SB(); __builtin_amdgcn_s_barrier(); SB();

    // ---- phase 2: B nh1 -> acc[0..3][2..3]; stage B23(k+1) ----
    Br[0][0] = rdB(b, 2, 0); Br[0][1] = rdB(b, 2, 1);
    Br[1][0] = rdB(b, 3, 0); Br[1][1] = rdB(b, 3, 1);
    if (pf1) { stB(b ^ 1, 2, k + 1); stB(b ^ 1, 3, k + 1); }
    SB(); __builtin_amdgcn_s_barrier(); SB();
    __builtin_amdgcn_s_setprio(1);
#pragma unroll
    for (int mf = 0; mf < 4; mf++)
#pragma unroll
      for (int nf = 0; nf < 2; nf++) {
        acc[mf][nf + 2] = __builtin_amdgcn_mfma_f32_16x16x32_bf16(
            Ar[mf][0], Br[nf][0], acc[mf][nf + 2], 0, 0, 0);
        acc[mf][nf + 2] = __builtin_amdgcn_mfma_f32_16x16x32_bf16(
            Ar[mf][1], Br[nf][1], acc[mf][nf + 2], 0, 0, 0);
      }
    __builtin_amdgcn_s_setprio(0);
    if (pf2) asm volatile("s_waitcnt vmcnt(6)" ::: "memory");
    else     asm volatile("s_waitcnt vmcnt(0)" ::: "memory");
    SB(); __builtin_amdgcn_s_barrier(); SB();

    // ---- phase 3: A mh1 + B nh0 -> acc[4..7][0..1]; stage A13(k+1) ----
#pragma unroll
    for (int mf = 0; mf < 4; mf++) {
      Ar[mf][0] = rdA(b, mf + 4, 0);
      Ar[mf][1] = rdA(b, mf + 4, 1);
    }
    Br[0][0] = rdB(b, 0, 0); Br[0][1] = rdB(b, 0, 1);
    Br[1][0] = rdB(b, 1, 0); Br[1][1] = rdB(b, 1, 1);
    if (pf1) { stA(b ^ 1, 1, k + 1); stA(b ^ 1, 3, k + 1); }
    SB(); __builtin_amdgcn_s_barrier(); SB();
    __builtin_amdgcn_s_setprio(1);
#pragma unroll
    for (int mf = 0; mf < 4; mf++)
#pragma unroll
      for (int nf = 0; nf < 2; nf++) {
        acc[mf + 4][nf] = __builtin_amdgcn_mfma_f32_16x16x32_bf16(
            Ar[mf][0], Br[nf][0], acc[mf + 4][nf], 0, 0, 0);
        acc[mf + 4][nf] = __builtin_amdgcn_mfma_f32_16x16x32_bf16(
            Ar[mf][1], Br[nf][1], acc[mf + 4][nf], 0, 0, 0);
      }
    __builtin_amdgcn_s_setprio(0);
    if (pf2) asm volatile("s_waitcnt vmcnt(6)" ::: "memory");
    else     asm volatile("s_waitcnt vmcnt(0)" ::: "memory");
    SB(); __builtin_amdgcn_s_barrier(); SB();

    // ---- phase 4: B nh1 -> acc[4..7][2..3]; stage A02(k+2) into buf b ----
    Br[0][0] = rdB(b, 2, 0); Br[0][1] = rdB(b, 2, 1);
    Br[1][0] = rdB(b, 3, 0); Br[1][1] = rdB(b, 3, 1);
    if (pf2) { stA(b, 0, k + 2); stA(b, 2, k + 2); }
    SB(); __builtin_amdgcn_s_barrier(); SB();
    __builtin_amdgcn_s_setprio(1);
#pragma unroll
    for (int mf = 0; mf < 4; mf++)
#pragma unroll
      for (int nf = 0; nf < 2; nf++) {
        acc[mf + 4][nf + 2] = __builtin_amdgcn_mfma_f32_16x16x32_bf16(
            Ar[mf][0], Br[nf][0], acc[mf + 4][nf + 2], 0, 0, 0);
        acc[mf + 4][nf + 2] = __builtin_amdgcn_mfma_f32_16x16x32_bf16(
            Ar[mf][1], Br[nf][1], acc[mf + 4][nf + 2], 0, 0, 0);
      }
    __builtin_amdgcn_s_setprio(0);
    if (pf2) asm volatile("s_waitcnt vmcnt(6)" ::: "memory");
    else     asm volatile("s_waitcnt vmcnt(0)" ::: "memory");
    SB(); __builtin_amdgcn_s_barrier(); SB();
  }

  // epilogue
#pragma unroll
  for (int mf = 0; mf < 8; mf++) {
#pragma unroll
    for (int nf = 0; nf < 4; nf++) {
      const int gr0 = m0 + wr * 128 + mf * 16 + lc * 4;
      const int gc = n0 + wc * 64 + nf * 16 + lr;
      const float bs = bias[gc];
#pragma unroll
      for (int r = 0; r < 4; r++) {
        const float v = acc[mf][nf][r] + bs;
        const int gr = gr0 + r;
        if (EPI == 0) {
          ((ushort*)outp)[(size_t)gr * N + gc] = f2bf(v);
        } else {
          const float gg = 0.5f * v * (1.0f + erff(v * 0.70710678118654752f));
          ((ushort*)outp)[(size_t)gr * N + gc] = f2bf(gg);
        }
      }
    }
  }
}

// ---------- flash attention (swapped operands) ----------
__global__ __launch_bounds__(256) void attn_kernel(
    const ushort* __restrict__ qkv, const ushort* __restrict__ vt,
    ushort* __restrict__ o_out) {
  __shared__ ushort sK[4096];
  __shared__ ushort sV[4096];
  __shared__ ushort sP[4 * 32 * 72];
  const int t = threadIdx.x;
  const int lane = t & 63, wid = t >> 6;
  const int lr = lane & 15, lc = lane >> 4;
  const int qb = blockIdx.x;
  const int bh = blockIdx.y;
  const int bidx = bh >> 4, h = bh & 15;
  const size_t base = (size_t)bidx * 1024 * 3072;
  const int q0w = qb * 128 + wid * 32;

  bf16x8 qf[2][2];
#pragma unroll
  for (int nf = 0; nf < 2; nf++)
#pragma unroll
    for (int kd = 0; kd < 2; kd++)
      qf[nf][kd] = *(const bf16x8*)&qkv[base +
          (size_t)(q0w + nf * 16 + lr) * 3072 + h * 64 + kd * 32 + lc * 8];

  f32x4 oacc[4][2];
#pragma unroll
  for (int mf = 0; mf < 4; mf++)
#pragma unroll
    for (int nf = 0; nf < 2; nf++) oacc[mf][nf] = (f32x4){0.f, 0.f, 0.f, 0.f};
  float m_r[2] = {-1e30f, -1e30f};
  float l_r[2] = {0.f, 0.f};

  const int srow = lane >> 2;
  const int scol = (lane & 3) * 8;
  ushort* pw = sP + wid * 2304;

  for (int kv0 = 0; kv0 < 1024; kv0 += 64) {
    __syncthreads();
#pragma unroll
    for (int s = 0; s < 2; s++) {
      gl_lds16(qkv + base + (size_t)(kv0 + wid * 16 + srow) * 3072 + 1024 +
                   h * 64 + s * 32 + scol,
               sK + s * 2048 + wid * 512);
      gl_lds16(vt + (size_t)(bh * 64 + wid * 16 + srow) * 1024 + kv0 + s * 32 +
                   scol,
               sV + s * 2048 + wid * 512);
    }
    __syncthreads();

    f32x4 st[4][2];
#pragma unroll
    for (int mf = 0; mf < 4; mf++) {
      bf16x8 ka0 = *(const bf16x8*)&sK[(mf * 16 + lr) * 32 + lc * 8];
      bf16x8 ka1 = *(const bf16x8*)&sK[2048 + (mf * 16 + lr) * 32 + lc * 8];
#pragma unroll
      for (int nf = 0; nf < 2; nf++) {
        f32x4 z = (f32x4){0.f, 0.f, 0.f, 0.f};
        z = __builtin_amdgcn_mfma_f32_16x16x32_bf16(ka0, qf[nf][0], z, 0, 0, 0);
        z = __builtin_amdgcn_mfma_f32_16x16x32_bf16(ka1, qf[nf][1], z, 0, 0, 0);
        st[mf][nf] = z;
      }
    }

#pragma unroll
    for (int nf = 0; nf < 2; nf++) {
      float mx = st[0][nf][0];
#pragma unroll
      for (int mf = 0; mf < 4; mf++)
        mx = fmaxf(mx, fmaxf(fmaxf(st[mf][nf][0], st[mf][nf][1]),
                             fmaxf(st[mf][nf][2], st[mf][nf][3])));
      mx = fmaxf(mx, __shfl_xor(mx, 16));
      mx = fmaxf(mx, __shfl_xor(mx, 32));
      mx *= 0.125f;
      const float mn = fmaxf(m_r[nf], mx);
      const float alpha = __expf(m_r[nf] - mn);
      m_r[nf] = mn;
      float rs = 0.f;
#pragma unroll
      for (int mf = 0; mf < 4; mf++) {
        const float p0 = __expf(fmaf(st[mf][nf][0], 0.125f, -mn));
        const float p1 = __expf(fmaf(st[mf][nf][1], 0.125f, -mn));
        const float p2 = __expf(fmaf(st[mf][nf][2], 0.125f, -mn));
        const float p3 = __expf(fmaf(st[mf][nf][3], 0.125f, -mn));
        rs += (p0 + p1) + (p2 + p3);
        uint2 u;
        u.x = (uint)f2bf(p0) | ((uint)f2bf(p1) << 16);
        u.y = (uint)f2bf(p2) | ((uint)f2bf(p3) << 16);
        *(uint2*)&pw[(nf * 16 + lr) * 72 + mf * 16 + lc * 4] = u;
      }
      rs += __shfl_xor(rs, 16);
      rs += __shfl_xor(rs, 32);
      l_r[nf] = l_r[nf] * alpha + rs;
#pragma unroll
      for (int mf = 0; mf < 4; mf++) {
        oacc[mf][nf][0] *= alpha;
        oacc[mf][nf][1] *= alpha;
        oacc[mf][nf][2] *= alpha;
        oacc[mf][nf][3] *= alpha;
      }
    }

#pragma unroll
    for (int ks = 0; ks < 2; ks++) {
      bf16x8 pb0 = *(const bf16x8*)&pw[lr * 72 + ks * 32 + lc * 8];
      bf16x8 pb1 = *(const bf16x8*)&pw[(16 + lr) * 72 + ks * 32 + lc * 8];
#pragma unroll
      for (int mf = 0; mf < 4; mf++) {
        bf16x8 va = *(const bf16x8*)&sV[ks * 2048 + (mf * 16 + lr) * 32 + lc * 8];
        oacc[mf][0] =
            __builtin_amdgcn_mfma_f32_16x16x32_bf16(va, pb0, oacc[mf][0], 0, 0, 0);
        oacc[mf][1] =
            __builtin_amdgcn_mfma_f32_16x16x32_bf16(va, pb1, oacc[mf][1], 0, 0, 0);
      }
    }
  }

  const float inv[2] = {1.f / l_r[0], 1.f / l_r[1]};
#pragma unroll
  for (int mf = 0; mf < 4; mf++)
#pragma unroll
    for (int nf = 0; nf < 2; nf++) {
      ushort4 o4;
      o4.x = f2bf(oacc[mf][nf][0] * inv[nf]);
      o4.y = f2bf(oacc[mf][nf][1] * inv[nf]);
      o4.z = f2bf(oacc[mf][nf][2] * inv[nf]);
      o4.w = f2bf(oacc[mf][nf][3] * inv[nf]);
      *(ushort4*)&o_out[(size_t)(bidx * 1024 + q0w + nf * 16 + lr) * 1024 +
                        h * 64 + mf * 16 + lc * 4] = o4;
    }
}

// ---------- launch ----------
extern "C" void kernel_launch(void* const* d_in, const int* in_sizes, int n_in,
                              void* d_out, int out_size, void* d_ws,
                              size_t ws_size, hipStream_t stream) {
  const float* x      = (const float*)d_in[0];
  const float* ln1_g  = (const float*)d_in[1];
  const float* ln1_b  = (const float*)d_in[2];
  const float* w_qkv  = (const float*)d_in[3];
  const float* b_qkv  = (const float*)d_in[4];
  const float* w_proj = (const float*)d_in[5];
  const float* b_proj = (const float*)d_in[6];
  const float* ln2_g  = (const float*)d_in[7];
  const float* ln2_b  = (const float*)d_in[8];
  const float* w_fc1  = (const float*)d_in[9];
  const float* b_fc1  = (const float*)d_in[10];
  const float* w_fc2  = (const float*)d_in[11];
  const float* b_fc2  = (const float*)d_in[12];
  float* out = (float*)d_out;

  ushort* ws      = (ushort*)d_ws;
  ushort* wt_qkv  = ws;                         // 3072*1024
  ushort* wt_proj = wt_qkv + 3072 * 1024;       // 1024*1024
  ushort* wt_fc1  = wt_proj + 1024 * 1024;      // 4096*1024
  ushort* wt_fc2  = wt_fc1 + 4096 * 1024;       // 1024*4096
  ushort* hbuf    = wt_fc2 + 1024 * 4096;       // 4096*1024
  ushort* qkv     = hbuf + 4096 * 1024;         // 4096*3072
  ushort* obuf    = qkv + 4096 * 3072;          // 4096*1024
  ushort* h3      = qkv;                        // aliases qkv+obuf
  ushort* vtb     = hbuf;                       // vt[64][64][1024]

  transpose_w<<<dim3(96, 32), dim3(32, 8), 0, stream>>>(w_qkv, wt_qkv, 1024, 3072);
  transpose_w<<<dim3(32, 32), dim3(32, 8), 0, stream>>>(w_proj, wt_proj, 1024, 1024);
  transpose_w<<<dim3(128, 32), dim3(32, 8), 0, stream>>>(w_fc1, wt_fc1, 1024, 4096);
  transpose_w<<<dim3(32, 128), dim3(32, 8), 0, stream>>>(w_fc2, wt_fc2, 4096, 1024);

  ln_bf16<<<4096, 256, 0, stream>>>(x, ln1_g, ln1_b, hbuf);
  gemm256<0><<<dim3(12, 16), 512, 0, stream>>>(hbuf, wt_qkv, b_qkv, qkv,
                                               4096, 3072, 1024);
  transpose_v<<<dim3(32, 2, 64), dim3(32, 8), 0, stream>>>(qkv, vtb);
  attn_kernel<<<dim3(8, 64), 256, 0, stream>>>(qkv, vtb, obuf);
  gemm_bt<2><<<dim3(8, 32), 256, 0, stream>>>(obuf, wt_proj, b_proj, x, out,
                                              4096, 1024, 1024);
  ln_bf16<<<4096, 256, 0, stream>>>(out, ln2_g, ln2_b, hbuf);
  gemm256<1><<<dim3(16, 16), 512, 0, stream>>>(hbuf, wt_fc1, b_fc1, h3,
                                               4096, 4096, 1024);
  gemm_bt<2><<<dim3(8, 32), 256, 0, stream>>>(h3, wt_fc2, b_fc2, out, out,
                                              4096, 1024, 4096);
}

// Round 6
// 250.239 us; speedup vs baseline: 1.3699x; 1.3699x over previous
//
#include <hip/hip_runtime.h>
#include <hip/hip_bf16.h>

// ---------- common types ----------
typedef __attribute__((ext_vector_type(8))) short bf16x8;
typedef __attribute__((ext_vector_type(4))) float f32x4;

__device__ __forceinline__ ushort f2bf(float f) {
  unsigned int u = __float_as_uint(f);
  u += 0x7fffu + ((u >> 16) & 1u);   // RNE
  return (ushort)(u >> 16);
}

__device__ __forceinline__ void gl_lds16(const void* g, void* l) {
  __builtin_amdgcn_global_load_lds(
      (const __attribute__((address_space(1))) void*)g,
      (__attribute__((address_space(3))) void*)l, 16, 0, 0);
}

#define SB() __builtin_amdgcn_sched_barrier(0)

// ---------- weight convert+transpose: W[K][N] f32 -> Wt[N][K] bf16 ----------
__global__ __launch_bounds__(256) void transpose_w(
    const float* __restrict__ W, ushort* __restrict__ Wt, int K, int N) {
  __shared__ float tile[32][33];
  const int tx = threadIdx.x, ty = threadIdx.y;  // (32, 8)
  const int bx = blockIdx.x, by = blockIdx.y;
#pragma unroll
  for (int j = 0; j < 4; j++)
    tile[ty + j * 8][tx] = W[(size_t)(by * 32 + ty + j * 8) * N + bx * 32 + tx];
  __syncthreads();
#pragma unroll
  for (int j = 0; j < 4; j++)
    Wt[(size_t)(bx * 32 + ty + j * 8) * K + by * 32 + tx] =
        f2bf(tile[tx][ty + j * 8]);
}

// ---------- V transpose: qkv V-part -> vt[bh][d][n] bf16 ----------
__global__ __launch_bounds__(256) void transpose_v(
    const ushort* __restrict__ qkv, ushort* __restrict__ vt) {
  __shared__ ushort tile[32][33];
  const int tx = threadIdx.x, ty = threadIdx.y;  // (32, 8)
  const int n0 = blockIdx.x * 32;
  const int d0 = blockIdx.y * 32;
  const int bh = blockIdx.z;
  const int bidx = bh >> 4, h = bh & 15;
#pragma unroll
  for (int j = 0; j < 4; j++)
    tile[ty + j * 8][tx] =
        qkv[(size_t)(bidx * 1024 + n0 + ty + j * 8) * 3072 + 2048 + h * 64 +
            d0 + tx];
  __syncthreads();
#pragma unroll
  for (int j = 0; j < 4; j++)
    vt[(size_t)(bh * 64 + d0 + ty + j * 8) * 1024 + n0 + tx] =
        tile[tx][ty + j * 8];
}

// ---------- layernorm: f32 row(1024) -> bf16 ----------
__global__ __launch_bounds__(256) void ln_bf16(
    const float* __restrict__ x, const float* __restrict__ g,
    const float* __restrict__ b, ushort* __restrict__ out) {
  const int row = blockIdx.x;
  const int t = threadIdx.x;
  float4 v = ((const float4*)(x + (size_t)row * 1024))[t];
  float s = v.x + v.y + v.z + v.w;
  float ss = v.x * v.x + v.y * v.y + v.z * v.z + v.w * v.w;
#pragma unroll
  for (int msk = 1; msk < 64; msk <<= 1) {
    s += __shfl_xor(s, msk);
    ss += __shfl_xor(ss, msk);
  }
  __shared__ float red[8];
  const int wv = t >> 6, ln = t & 63;
  if (ln == 0) { red[wv * 2] = s; red[wv * 2 + 1] = ss; }
  __syncthreads();
  s = red[0] + red[2] + red[4] + red[6];
  ss = red[1] + red[3] + red[5] + red[7];
  const float mu = s * (1.0f / 1024.0f);
  const float var = ss * (1.0f / 1024.0f) - mu * mu;
  const float rstd = rsqrtf(var + 1e-5f);
  float4 gv = ((const float4*)g)[t];
  float4 bv = ((const float4*)b)[t];
  ushort4 o;
  o.x = f2bf((v.x - mu) * rstd * gv.x + bv.x);
  o.y = f2bf((v.y - mu) * rstd * gv.y + bv.y);
  o.z = f2bf((v.z - mu) * rstd * gv.z + bv.z);
  o.w = f2bf((v.w - mu) * rstd * gv.w + bv.w);
  ((ushort4*)(out + (size_t)row * 1024))[t] = o;
}

// ---------- 2-phase double-buffered GEMM (T3 minimum recipe) ----------
// C[M][N] = A[M][K](bf16) * Bt[N][K]^T(bf16) + bias, epilogue by EPI.
// EPI 0: bias -> bf16. EPI 1: bias+GELU -> bf16. EPI 2: bias+resid(f32) -> f32.
// Geometry: BM x BN tile, BK=64, NW waves (2 x NW/2 wave grid).
// Sync: ONE vmcnt(0) + barrier per K-tile — robust to any extra vmem ops
// (no counted vmcnt anywhere).
// LDS swizzle (T2): 16B-unit u_phys = u_log ^ (row & 7) applied on BOTH the
// global source of global_load_lds (dest linear) and the ds_read address;
// 8 lanes per bank-quad per b128 read = conflict-free.
template <int BM, int BN, int NW, int EPI>
__global__ __launch_bounds__(NW * 64, 2) void gemm2ph(
    const ushort* __restrict__ A, const ushort* __restrict__ Bt,
    const float* __restrict__ bias, const float* __restrict__ resid,
    void* __restrict__ outp, int M, int N, int K) {
  constexpr int T = NW * 64;
  constexpr int WN = NW / 2;         // wave cols
  constexpr int MF = BM / 2 / 16;    // A frags per wave
  constexpr int NF = BN / WN / 16;   // B frags per wave (=4)
  constexpr int CA = BM / 64, CB = BN / 64;
  constexpr int REP = 512 / T;
  __shared__ ushort smem[2 * (BM + BN) * 64];
  const int t = threadIdx.x;
  const int lane = t & 63, wid = t >> 6;
  const int lr = lane & 15, lc = lane >> 4;
  const int wr = wid / WN, wc = wid % WN;
  const int m0 = blockIdx.y * BM, n0 = blockIdx.x * BN;
  const int nkt = K >> 6;

  // staging: chunk = 64 rows x 8 x 16B units; thread covers row (r*T+t)>>3,
  // phys unit t&7, logical unit (t&7)^((t>>3)&7)  (row&7 == (t>>3)&7).
  const int uoff = ((t & 7) ^ ((t >> 3) & 7)) * 8;
  const int sx = lr & 7;
  const int au0 = (lc ^ sx) * 8;            // phys unit, kk=0
  const int au1 = ((lc | 4) ^ sx) * 8;      // phys unit, kk=1

  f32x4 acc[MF][NF];
#pragma unroll
  for (int m = 0; m < MF; m++)
#pragma unroll
    for (int n = 0; n < NF; n++) acc[m][n] = (f32x4){0.f, 0.f, 0.f, 0.f};

  auto stage = [&](int bb, int kt) {
#pragma unroll
    for (int c = 0; c < CA; c++)
#pragma unroll
      for (int r = 0; r < REP; r++)
        gl_lds16(A + (size_t)(m0 + c * 64 + ((r * T + t) >> 3)) * K +
                     (size_t)(kt * 64) + uoff,
                 &smem[bb * BM * 64 + c * 4096 + (r * T + wid * 64) * 8]);
#pragma unroll
    for (int c = 0; c < CB; c++)
#pragma unroll
      for (int r = 0; r < REP; r++)
        gl_lds16(Bt + (size_t)(n0 + c * 64 + ((r * T + t) >> 3)) * K +
                     (size_t)(kt * 64) + uoff,
                 &smem[2 * BM * 64 + bb * BN * 64 + c * 4096 +
                       (r * T + wid * 64) * 8]);
  };
  auto rdA = [&](int bb, int mf, int kk) {
    return *(const bf16x8*)&smem[bb * BM * 64 +
                                 (wr * (BM / 2) + mf * 16 + lr) * 64 +
                                 (kk ? au1 : au0)];
  };
  auto rdB = [&](int bb, int nf, int kk) {
    return *(const bf16x8*)&smem[2 * BM * 64 + bb * BN * 64 +
                                 (wc * 64 + nf * 16 + lr) * 64 +
                                 (kk ? au1 : au0)];
  };

  // prologue
  stage(0, 0);
  asm volatile("s_waitcnt vmcnt(0)" ::: "memory");
  SB(); __builtin_amdgcn_s_barrier(); SB();

  int b = 0;
  for (int kt = 0; kt < nkt; kt++, b ^= 1) {
    if (kt + 1 < nkt) stage(b ^ 1, kt + 1);

    bf16x8 Br[NF][2];
#pragma unroll
    for (int nf = 0; nf < NF; nf++) {
      Br[nf][0] = rdB(b, nf, 0);
      Br[nf][1] = rdB(b, nf, 1);
    }
#pragma unroll
    for (int mh = 0; mh < MF / 4; mh++) {
      bf16x8 Ar[4][2];
#pragma unroll
      for (int mf = 0; mf < 4; mf++) {
        Ar[mf][0] = rdA(b, mh * 4 + mf, 0);
        Ar[mf][1] = rdA(b, mh * 4 + mf, 1);
      }
      __builtin_amdgcn_s_setprio(1);
#pragma unroll
      for (int mf = 0; mf < 4; mf++)
#pragma unroll
        for (int nf = 0; nf < NF; nf++) {
          acc[mh * 4 + mf][nf] = __builtin_amdgcn_mfma_f32_16x16x32_bf16(
              Ar[mf][0], Br[nf][0], acc[mh * 4 + mf][nf], 0, 0, 0);
          acc[mh * 4 + mf][nf] = __builtin_amdgcn_mfma_f32_16x16x32_bf16(
              Ar[mf][1], Br[nf][1], acc[mh * 4 + mf][nf], 0, 0, 0);
        }
      __builtin_amdgcn_s_setprio(0);
    }

    asm volatile("s_waitcnt vmcnt(0)" ::: "memory");
    SB(); __builtin_amdgcn_s_barrier(); SB();
  }

  // epilogue
#pragma unroll
  for (int mf = 0; mf < MF; mf++) {
#pragma unroll
    for (int nf = 0; nf < NF; nf++) {
      const int gr0 = m0 + wr * (BM / 2) + mf * 16 + lc * 4;
      const int gc = n0 + wc * 64 + nf * 16 + lr;
      const float bs = bias[gc];
#pragma unroll
      for (int r = 0; r < 4; r++) {
        const float v = acc[mf][nf][r] + bs;
        const int gr = gr0 + r;
        if (EPI == 0) {
          ((ushort*)outp)[(size_t)gr * N + gc] = f2bf(v);
        } else if (EPI == 1) {
          const float gg = 0.5f * v * (1.0f + erff(v * 0.70710678118654752f));
          ((ushort*)outp)[(size_t)gr * N + gc] = f2bf(gg);
        } else {
          ((float*)outp)[(size_t)gr * N + gc] =
              v + resid[(size_t)gr * N + gc];
        }
      }
    }
  }
}

// ---------- flash attention (swapped operands) ----------
__global__ __launch_bounds__(256) void attn_kernel(
    const ushort* __restrict__ qkv, const ushort* __restrict__ vt,
    ushort* __restrict__ o_out) {
  __shared__ ushort sK[4096];
  __shared__ ushort sV[4096];
  __shared__ ushort sP[4 * 32 * 72];
  const int t = threadIdx.x;
  const int lane = t & 63, wid = t >> 6;
  const int lr = lane & 15, lc = lane >> 4;
  const int qb = blockIdx.x;
  const int bh = blockIdx.y;
  const int bidx = bh >> 4, h = bh & 15;
  const size_t base = (size_t)bidx * 1024 * 3072;
  const int q0w = qb * 128 + wid * 32;

  bf16x8 qf[2][2];
#pragma unroll
  for (int nf = 0; nf < 2; nf++)
#pragma unroll
    for (int kd = 0; kd < 2; kd++)
      qf[nf][kd] = *(const bf16x8*)&qkv[base +
          (size_t)(q0w + nf * 16 + lr) * 3072 + h * 64 + kd * 32 + lc * 8];

  f32x4 oacc[4][2];
#pragma unroll
  for (int mf = 0; mf < 4; mf++)
#pragma unroll
    for (int nf = 0; nf < 2; nf++) oacc[mf][nf] = (f32x4){0.f, 0.f, 0.f, 0.f};
  float m_r[2] = {-1e30f, -1e30f};
  float l_r[2] = {0.f, 0.f};

  const int srow = lane >> 2;
  const int scol = (lane & 3) * 8;
  ushort* pw = sP + wid * 2304;

  for (int kv0 = 0; kv0 < 1024; kv0 += 64) {
    __syncthreads();
#pragma unroll
    for (int s = 0; s < 2; s++) {
      gl_lds16(qkv + base + (size_t)(kv0 + wid * 16 + srow) * 3072 + 1024 +
                   h * 64 + s * 32 + scol,
               sK + s * 2048 + wid * 512);
      gl_lds16(vt + (size_t)(bh * 64 + wid * 16 + srow) * 1024 + kv0 + s * 32 +
                   scol,
               sV + s * 2048 + wid * 512);
    }
    __syncthreads();

    f32x4 st[4][2];
#pragma unroll
    for (int mf = 0; mf < 4; mf++) {
      bf16x8 ka0 = *(const bf16x8*)&sK[(mf * 16 + lr) * 32 + lc * 8];
      bf16x8 ka1 = *(const bf16x8*)&sK[2048 + (mf * 16 + lr) * 32 + lc * 8];
#pragma unroll
      for (int nf = 0; nf < 2; nf++) {
        f32x4 z = (f32x4){0.f, 0.f, 0.f, 0.f};
        z = __builtin_amdgcn_mfma_f32_16x16x32_bf16(ka0, qf[nf][0], z, 0, 0, 0);
        z = __builtin_amdgcn_mfma_f32_16x16x32_bf16(ka1, qf[nf][1], z, 0, 0, 0);
        st[mf][nf] = z;
      }
    }

#pragma unroll
    for (int nf = 0; nf < 2; nf++) {
      float mx = st[0][nf][0];
#pragma unroll
      for (int mf = 0; mf < 4; mf++)
        mx = fmaxf(mx, fmaxf(fmaxf(st[mf][nf][0], st[mf][nf][1]),
                             fmaxf(st[mf][nf][2], st[mf][nf][3])));
      mx = fmaxf(mx, __shfl_xor(mx, 16));
      mx = fmaxf(mx, __shfl_xor(mx, 32));
      mx *= 0.125f;
      const float mn = fmaxf(m_r[nf], mx);
      const float alpha = __expf(m_r[nf] - mn);
      m_r[nf] = mn;
      float rs = 0.f;
#pragma unroll
      for (int mf = 0; mf < 4; mf++) {
        const float p0 = __expf(fmaf(st[mf][nf][0], 0.125f, -mn));
        const float p1 = __expf(fmaf(st[mf][nf][1], 0.125f, -mn));
        const float p2 = __expf(fmaf(st[mf][nf][2], 0.125f, -mn));
        const float p3 = __expf(fmaf(st[mf][nf][3], 0.125f, -mn));
        rs += (p0 + p1) + (p2 + p3);
        uint2 u;
        u.x = (uint)f2bf(p0) | ((uint)f2bf(p1) << 16);
        u.y = (uint)f2bf(p2) | ((uint)f2bf(p3) << 16);
        *(uint2*)&pw[(nf * 16 + lr) * 72 + mf * 16 + lc * 4] = u;
      }
      rs += __shfl_xor(rs, 16);
      rs += __shfl_xor(rs, 32);
      l_r[nf] = l_r[nf] * alpha + rs;
#pragma unroll
      for (int mf = 0; mf < 4; mf++) {
        oacc[mf][nf][0] *= alpha;
        oacc[mf][nf][1] *= alpha;
        oacc[mf][nf][2] *= alpha;
        oacc[mf][nf][3] *= alpha;
      }
    }

#pragma unroll
    for (int ks = 0; ks < 2; ks++) {
      bf16x8 pb0 = *(const bf16x8*)&pw[lr * 72 + ks * 32 + lc * 8];
      bf16x8 pb1 = *(const bf16x8*)&pw[(16 + lr) * 72 + ks * 32 + lc * 8];
#pragma unroll
      for (int mf = 0; mf < 4; mf++) {
        bf16x8 va = *(const bf16x8*)&sV[ks * 2048 + (mf * 16 + lr) * 32 + lc * 8];
        oacc[mf][0] =
            __builtin_amdgcn_mfma_f32_16x16x32_bf16(va, pb0, oacc[mf][0], 0, 0, 0);
        oacc[mf][1] =
            __builtin_amdgcn_mfma_f32_16x16x32_bf16(va, pb1, oacc[mf][1], 0, 0, 0);
      }
    }
  }

  const float inv[2] = {1.f / l_r[0], 1.f / l_r[1]};
#pragma unroll
  for (int mf = 0; mf < 4; mf++)
#pragma unroll
    for (int nf = 0; nf < 2; nf++) {
      ushort4 o4;
      o4.x = f2bf(oacc[mf][nf][0] * inv[nf]);
      o4.y = f2bf(oacc[mf][nf][1] * inv[nf]);
      o4.z = f2bf(oacc[mf][nf][2] * inv[nf]);
      o4.w = f2bf(oacc[mf][nf][3] * inv[nf]);
      *(ushort4*)&o_out[(size_t)(bidx * 1024 + q0w + nf * 16 + lr) * 1024 +
                        h * 64 + mf * 16 + lc * 4] = o4;
    }
}

// ---------- launch ----------
extern "C" void kernel_launch(void* const* d_in, const int* in_sizes, int n_in,
                              void* d_out, int out_size, void* d_ws,
                              size_t ws_size, hipStream_t stream) {
  const float* x      = (const float*)d_in[0];
  const float* ln1_g  = (const float*)d_in[1];
  const float* ln1_b  = (const float*)d_in[2];
  const float* w_qkv  = (const float*)d_in[3];
  const float* b_qkv  = (const float*)d_in[4];
  const float* w_proj = (const float*)d_in[5];
  const float* b_proj = (const float*)d_in[6];
  const float* ln2_g  = (const float*)d_in[7];
  const float* ln2_b  = (const float*)d_in[8];
  const float* w_fc1  = (const float*)d_in[9];
  const float* b_fc1  = (const float*)d_in[10];
  const float* w_fc2  = (const float*)d_in[11];
  const float* b_fc2  = (const float*)d_in[12];
  float* out = (float*)d_out;

  ushort* ws      = (ushort*)d_ws;
  ushort* wt_qkv  = ws;                         // 3072*1024
  ushort* wt_proj = wt_qkv + 3072 * 1024;       // 1024*1024
  ushort* wt_fc1  = wt_proj + 1024 * 1024;      // 4096*1024
  ushort* wt_fc2  = wt_fc1 + 4096 * 1024;       // 1024*4096
  ushort* hbuf    = wt_fc2 + 1024 * 4096;       // 4096*1024
  ushort* qkv     = hbuf + 4096 * 1024;         // 4096*3072
  ushort* obuf    = qkv + 4096 * 3072;          // 4096*1024
  ushort* h3      = qkv;                        // aliases qkv+obuf
  ushort* vtb     = hbuf;                       // vt[64][64][1024]

  transpose_w<<<dim3(96, 32), dim3(32, 8), 0, stream>>>(w_qkv, wt_qkv, 1024, 3072);
  transpose_w<<<dim3(32, 32), dim3(32, 8), 0, stream>>>(w_proj, wt_proj, 1024, 1024);
  transpose_w<<<dim3(128, 32), dim3(32, 8), 0, stream>>>(w_fc1, wt_fc1, 1024, 4096);
  transpose_w<<<dim3(32, 128), dim3(32, 8), 0, stream>>>(w_fc2, wt_fc2, 4096, 1024);

  ln_bf16<<<4096, 256, 0, stream>>>(x, ln1_g, ln1_b, hbuf);
  // QKV: 128^2 tile, 768 blocks (3/CU)
  gemm2ph<128, 128, 4, 0><<<dim3(24, 32), 256, 0, stream>>>(
      hbuf, wt_qkv, b_qkv, nullptr, qkv, 4096, 3072, 1024);
  transpose_v<<<dim3(32, 2, 64), dim3(32, 8), 0, stream>>>(qkv, vtb);
  attn_kernel<<<dim3(8, 64), 256, 0, stream>>>(qkv, vtb, obuf);
  // proj + residual -> f32 out
  gemm2ph<128, 128, 4, 2><<<dim3(8, 32), 256, 0, stream>>>(
      obuf, wt_proj, b_proj, x, out, 4096, 1024, 1024);
  ln_bf16<<<4096, 256, 0, stream>>>(out, ln2_g, ln2_b, hbuf);
  // fc1 + GELU: 256^2 tile, 256 blocks (1/CU)
  gemm2ph<256, 256, 8, 1><<<dim3(16, 16), 512, 0, stream>>>(
      hbuf, wt_fc1, b_fc1, nullptr, h3, 4096, 4096, 1024);
  // fc2 + residual -> f32 out
  gemm2ph<128, 128, 4, 2><<<dim3(8, 32), 256, 0, stream>>>(
      h3, wt_fc2, b_fc2, out, out, 4096, 1024, 4096);
}

// Round 7
// 223.057 us; speedup vs baseline: 1.5369x; 1.1219x over previous
//
#include <hip/hip_runtime.h>
#include <hip/hip_bf16.h>

// ---------- common types ----------
typedef __attribute__((ext_vector_type(8))) short bf16x8;
typedef __attribute__((ext_vector_type(4))) float f32x4;

__device__ __forceinline__ ushort f2bf(float f) {
  unsigned int u = __float_as_uint(f);
  u += 0x7fffu + ((u >> 16) & 1u);   // RNE
  return (ushort)(u >> 16);
}

__device__ __forceinline__ void gl_lds16(const void* g, void* l) {
  __builtin_amdgcn_global_load_lds(
      (const __attribute__((address_space(1))) void*)g,
      (__attribute__((address_space(3))) void*)l, 16, 0, 0);
}

#define SB() __builtin_amdgcn_sched_barrier(0)

// ---------- weight convert+transpose: W[K][N] f32 -> Wt[N][K] bf16 ----------
__global__ __launch_bounds__(256) void transpose_w(
    const float* __restrict__ W, ushort* __restrict__ Wt, int K, int N) {
  __shared__ float tile[32][33];
  const int tx = threadIdx.x, ty = threadIdx.y;  // (32, 8)
  const int bx = blockIdx.x, by = blockIdx.y;
#pragma unroll
  for (int j = 0; j < 4; j++)
    tile[ty + j * 8][tx] = W[(size_t)(by * 32 + ty + j * 8) * N + bx * 32 + tx];
  __syncthreads();
#pragma unroll
  for (int j = 0; j < 4; j++)
    Wt[(size_t)(bx * 32 + ty + j * 8) * K + by * 32 + tx] =
        f2bf(tile[tx][ty + j * 8]);
}

// ---------- V transpose: qkv V-part -> vt[bh][d][n] bf16 ----------
__global__ __launch_bounds__(256) void transpose_v(
    const ushort* __restrict__ qkv, ushort* __restrict__ vt) {
  __shared__ ushort tile[32][33];
  const int tx = threadIdx.x, ty = threadIdx.y;  // (32, 8)
  const int n0 = blockIdx.x * 32;
  const int d0 = blockIdx.y * 32;
  const int bh = blockIdx.z;
  const int bidx = bh >> 4, h = bh & 15;
#pragma unroll
  for (int j = 0; j < 4; j++)
    tile[ty + j * 8][tx] =
        qkv[(size_t)(bidx * 1024 + n0 + ty + j * 8) * 3072 + 2048 + h * 64 +
            d0 + tx];
  __syncthreads();
#pragma unroll
  for (int j = 0; j < 4; j++)
    vt[(size_t)(bh * 64 + d0 + ty + j * 8) * 1024 + n0 + tx] =
        tile[tx][ty + j * 8];
}

// ---------- layernorm: f32 row(1024) -> bf16 ----------
__global__ __launch_bounds__(256) void ln_bf16(
    const float* __restrict__ x, const float* __restrict__ g,
    const float* __restrict__ b, ushort* __restrict__ out) {
  const int row = blockIdx.x;
  const int t = threadIdx.x;
  float4 v = ((const float4*)(x + (size_t)row * 1024))[t];
  float s = v.x + v.y + v.z + v.w;
  float ss = v.x * v.x + v.y * v.y + v.z * v.z + v.w * v.w;
#pragma unroll
  for (int msk = 1; msk < 64; msk <<= 1) {
    s += __shfl_xor(s, msk);
    ss += __shfl_xor(ss, msk);
  }
  __shared__ float red[8];
  const int wv = t >> 6, ln = t & 63;
  if (ln == 0) { red[wv * 2] = s; red[wv * 2 + 1] = ss; }
  __syncthreads();
  s = red[0] + red[2] + red[4] + red[6];
  ss = red[1] + red[3] + red[5] + red[7];
  const float mu = s * (1.0f / 1024.0f);
  const float var = ss * (1.0f / 1024.0f) - mu * mu;
  const float rstd = rsqrtf(var + 1e-5f);
  float4 gv = ((const float4*)g)[t];
  float4 bv = ((const float4*)b)[t];
  ushort4 o;
  o.x = f2bf((v.x - mu) * rstd * gv.x + bv.x);
  o.y = f2bf((v.y - mu) * rstd * gv.y + bv.y);
  o.z = f2bf((v.z - mu) * rstd * gv.z + bv.z);
  o.w = f2bf((v.w - mu) * rstd * gv.w + bv.w);
  ((ushort4*)(out + (size_t)row * 1024))[t] = o;
}

// ---------- 2-phase double-buffered GEMM (T3 minimum recipe) ----------
// C[M][N] = A[M][K](bf16) * Bt[N][K]^T(bf16) + bias, epilogue by EPI.
// EPI 0: bias -> bf16. EPI 1: bias+GELU -> bf16. EPI 2: bias+resid(f32) -> f32.
// Sync: ONE vmcnt(0) + barrier per K-tile (no counted vmcnt — deterministic
// regardless of extra codegen vmem ops).
// T2 swizzle: 16B-unit u_phys = u_log ^ (row & 7) on BOTH gl_lds source and
// ds_read address (verified: 0 bank conflicts in r6).
// T1: XCD-rectangle block swizzle: hw-flat id -> (xcd, i); each XCD owns a
// cw x ch rectangle of tiles. Requires cw*xw == gridDim.x and
// ch*(8/xw) == gridDim.y (exact bijection).
template <int BM, int BN, int NW, int EPI>
__global__ __launch_bounds__(NW * 64, 2) void gemm2ph(
    const ushort* __restrict__ A, const ushort* __restrict__ Bt,
    const float* __restrict__ bias, const float* __restrict__ resid,
    void* __restrict__ outp, int M, int N, int K, int cw, int ch, int xw) {
  constexpr int T = NW * 64;
  constexpr int WN = NW / 2;         // wave cols
  constexpr int BWN = BN / WN;       // B rows per wave col
  constexpr int MF = BM / 2 / 16;    // A frags per wave
  constexpr int NF = BWN / 16;       // B frags per wave
  constexpr int CA = BM / 64, CB = BN / 64;
  constexpr int REP = 512 / T;
  __shared__ ushort smem[2 * (BM + BN) * 64];
  const int t = threadIdx.x;
  const int lane = t & 63, wid = t >> 6;
  const int lr = lane & 15, lc = lane >> 4;
  const int wr = wid / WN, wc = wid % WN;

  // XCD-rectangle swizzle
  const int flat = blockIdx.y * gridDim.x + blockIdx.x;
  const int xcd = flat & 7, li = flat >> 3;
  const int bx = (xcd % xw) * cw + (li % cw);
  const int by = (xcd / xw) * ch + (li / cw);
  const int m0 = by * BM, n0 = bx * BN;
  const int nkt = K >> 6;

  const int uoff = ((t & 7) ^ ((t >> 3) & 7)) * 8;
  const int sx = lr & 7;
  const int au0 = (lc ^ sx) * 8;            // phys unit, kk=0
  const int au1 = ((lc | 4) ^ sx) * 8;      // phys unit, kk=1

  f32x4 acc[MF][NF];
#pragma unroll
  for (int m = 0; m < MF; m++)
#pragma unroll
    for (int n = 0; n < NF; n++) acc[m][n] = (f32x4){0.f, 0.f, 0.f, 0.f};

  auto stage = [&](int bb, int kt) {
#pragma unroll
    for (int c = 0; c < CA; c++)
#pragma unroll
      for (int r = 0; r < REP; r++)
        gl_lds16(A + (size_t)(m0 + c * 64 + ((r * T + t) >> 3)) * K +
                     (size_t)(kt * 64) + uoff,
                 &smem[bb * BM * 64 + c * 4096 + (r * T + wid * 64) * 8]);
#pragma unroll
    for (int c = 0; c < CB; c++)
#pragma unroll
      for (int r = 0; r < REP; r++)
        gl_lds16(Bt + (size_t)(n0 + c * 64 + ((r * T + t) >> 3)) * K +
                     (size_t)(kt * 64) + uoff,
                 &smem[2 * BM * 64 + bb * BN * 64 + c * 4096 +
                       (r * T + wid * 64) * 8]);
  };
  auto rdA = [&](int bb, int mf, int kk) {
    return *(const bf16x8*)&smem[bb * BM * 64 +
                                 (wr * (BM / 2) + mf * 16 + lr) * 64 +
                                 (kk ? au1 : au0)];
  };
  auto rdB = [&](int bb, int nf, int kk) {
    return *(const bf16x8*)&smem[2 * BM * 64 + bb * BN * 64 +
                                 (wc * BWN + nf * 16 + lr) * 64 +
                                 (kk ? au1 : au0)];
  };

  // prologue
  stage(0, 0);
  asm volatile("s_waitcnt vmcnt(0)" ::: "memory");
  SB(); __builtin_amdgcn_s_barrier(); SB();

  int b = 0;
  for (int kt = 0; kt < nkt; kt++, b ^= 1) {
    if (kt + 1 < nkt) stage(b ^ 1, kt + 1);

    bf16x8 Br[NF][2];
#pragma unroll
    for (int nf = 0; nf < NF; nf++) {
      Br[nf][0] = rdB(b, nf, 0);
      Br[nf][1] = rdB(b, nf, 1);
    }
#pragma unroll
    for (int mh = 0; mh < MF / 4; mh++) {
      bf16x8 Ar[4][2];
#pragma unroll
      for (int mf = 0; mf < 4; mf++) {
        Ar[mf][0] = rdA(b, mh * 4 + mf, 0);
        Ar[mf][1] = rdA(b, mh * 4 + mf, 1);
      }
      __builtin_amdgcn_s_setprio(1);
#pragma unroll
      for (int mf = 0; mf < 4; mf++)
#pragma unroll
        for (int nf = 0; nf < NF; nf++) {
          acc[mh * 4 + mf][nf] = __builtin_amdgcn_mfma_f32_16x16x32_bf16(
              Ar[mf][0], Br[nf][0], acc[mh * 4 + mf][nf], 0, 0, 0);
          acc[mh * 4 + mf][nf] = __builtin_amdgcn_mfma_f32_16x16x32_bf16(
              Ar[mf][1], Br[nf][1], acc[mh * 4 + mf][nf], 0, 0, 0);
        }
      __builtin_amdgcn_s_setprio(0);
    }

    asm volatile("s_waitcnt vmcnt(0)" ::: "memory");
    SB(); __builtin_amdgcn_s_barrier(); SB();
  }

  // epilogue
#pragma unroll
  for (int mf = 0; mf < MF; mf++) {
#pragma unroll
    for (int nf = 0; nf < NF; nf++) {
      const int gr0 = m0 + wr * (BM / 2) + mf * 16 + lc * 4;
      const int gc = n0 + wc * BWN + nf * 16 + lr;
      const float bs = bias[gc];
#pragma unroll
      for (int r = 0; r < 4; r++) {
        const float v = acc[mf][nf][r] + bs;
        const int gr = gr0 + r;
        if (EPI == 0) {
          ((ushort*)outp)[(size_t)gr * N + gc] = f2bf(v);
        } else if (EPI == 1) {
          const float gg = 0.5f * v * (1.0f + erff(v * 0.70710678118654752f));
          ((ushort*)outp)[(size_t)gr * N + gc] = f2bf(gg);
        } else {
          ((float*)outp)[(size_t)gr * N + gc] =
              v + resid[(size_t)gr * N + gc];
        }
      }
    }
  }
}

// ---------- flash attention (swapped operands) ----------
__global__ __launch_bounds__(256) void attn_kernel(
    const ushort* __restrict__ qkv, const ushort* __restrict__ vt,
    ushort* __restrict__ o_out) {
  __shared__ ushort sK[4096];
  __shared__ ushort sV[4096];
  __shared__ ushort sP[4 * 32 * 72];
  const int t = threadIdx.x;
  const int lane = t & 63, wid = t >> 6;
  const int lr = lane & 15, lc = lane >> 4;
  const int qb = blockIdx.x;
  const int bh = blockIdx.y;
  const int bidx = bh >> 4, h = bh & 15;
  const size_t base = (size_t)bidx * 1024 * 3072;
  const int q0w = qb * 128 + wid * 32;

  bf16x8 qf[2][2];
#pragma unroll
  for (int nf = 0; nf < 2; nf++)
#pragma unroll
    for (int kd = 0; kd < 2; kd++)
      qf[nf][kd] = *(const bf16x8*)&qkv[base +
          (size_t)(q0w + nf * 16 + lr) * 3072 + h * 64 + kd * 32 + lc * 8];

  f32x4 oacc[4][2];
#pragma unroll
  for (int mf = 0; mf < 4; mf++)
#pragma unroll
    for (int nf = 0; nf < 2; nf++) oacc[mf][nf] = (f32x4){0.f, 0.f, 0.f, 0.f};
  float m_r[2] = {-1e30f, -1e30f};
  float l_r[2] = {0.f, 0.f};

  const int srow = lane >> 2;
  const int scol = (lane & 3) * 8;
  ushort* pw = sP + wid * 2304;

  for (int kv0 = 0; kv0 < 1024; kv0 += 64) {
    __syncthreads();
#pragma unroll
    for (int s = 0; s < 2; s++) {
      gl_lds16(qkv + base + (size_t)(kv0 + wid * 16 + srow) * 3072 + 1024 +
                   h * 64 + s * 32 + scol,
               sK + s * 2048 + wid * 512);
      gl_lds16(vt + (size_t)(bh * 64 + wid * 16 + srow) * 1024 + kv0 + s * 32 +
                   scol,
               sV + s * 2048 + wid * 512);
    }
    __syncthreads();

    f32x4 st[4][2];
#pragma unroll
    for (int mf = 0; mf < 4; mf++) {
      bf16x8 ka0 = *(const bf16x8*)&sK[(mf * 16 + lr) * 32 + lc * 8];
      bf16x8 ka1 = *(const bf16x8*)&sK[2048 + (mf * 16 + lr) * 32 + lc * 8];
#pragma unroll
      for (int nf = 0; nf < 2; nf++) {
        f32x4 z = (f32x4){0.f, 0.f, 0.f, 0.f};
        z = __builtin_amdgcn_mfma_f32_16x16x32_bf16(ka0, qf[nf][0], z, 0, 0, 0);
        z = __builtin_amdgcn_mfma_f32_16x16x32_bf16(ka1, qf[nf][1], z, 0, 0, 0);
        st[mf][nf] = z;
      }
    }

#pragma unroll
    for (int nf = 0; nf < 2; nf++) {
      float mx = st[0][nf][0];
#pragma unroll
      for (int mf = 0; mf < 4; mf++)
        mx = fmaxf(mx, fmaxf(fmaxf(st[mf][nf][0], st[mf][nf][1]),
                             fmaxf(st[mf][nf][2], st[mf][nf][3])));
      mx = fmaxf(mx, __shfl_xor(mx, 16));
      mx = fmaxf(mx, __shfl_xor(mx, 32));
      mx *= 0.125f;
      const float mn = fmaxf(m_r[nf], mx);
      const float alpha = __expf(m_r[nf] - mn);
      m_r[nf] = mn;
      float rs = 0.f;
#pragma unroll
      for (int mf = 0; mf < 4; mf++) {
        const float p0 = __expf(fmaf(st[mf][nf][0], 0.125f, -mn));
        const float p1 = __expf(fmaf(st[mf][nf][1], 0.125f, -mn));
        const float p2 = __expf(fmaf(st[mf][nf][2], 0.125f, -mn));
        const float p3 = __expf(fmaf(st[mf][nf][3], 0.125f, -mn));
        rs += (p0 + p1) + (p2 + p3);
        uint2 u;
        u.x = (uint)f2bf(p0) | ((uint)f2bf(p1) << 16);
        u.y = (uint)f2bf(p2) | ((uint)f2bf(p3) << 16);
        *(uint2*)&pw[(nf * 16 + lr) * 72 + mf * 16 + lc * 4] = u;
      }
      rs += __shfl_xor(rs, 16);
      rs += __shfl_xor(rs, 32);
      l_r[nf] = l_r[nf] * alpha + rs;
#pragma unroll
      for (int mf = 0; mf < 4; mf++) {
        oacc[mf][nf][0] *= alpha;
        oacc[mf][nf][1] *= alpha;
        oacc[mf][nf][2] *= alpha;
        oacc[mf][nf][3] *= alpha;
      }
    }

#pragma unroll
    for (int ks = 0; ks < 2; ks++) {
      bf16x8 pb0 = *(const bf16x8*)&pw[lr * 72 + ks * 32 + lc * 8];
      bf16x8 pb1 = *(const bf16x8*)&pw[(16 + lr) * 72 + ks * 32 + lc * 8];
#pragma unroll
      for (int mf = 0; mf < 4; mf++) {
        bf16x8 va = *(const bf16x8*)&sV[ks * 2048 + (mf * 16 + lr) * 32 + lc * 8];
        oacc[mf][0] =
            __builtin_amdgcn_mfma_f32_16x16x32_bf16(va, pb0, oacc[mf][0], 0, 0, 0);
        oacc[mf][1] =
            __builtin_amdgcn_mfma_f32_16x16x32_bf16(va, pb1, oacc[mf][1], 0, 0, 0);
      }
    }
  }

  const float inv[2] = {1.f / l_r[0], 1.f / l_r[1]};
#pragma unroll
  for (int mf = 0; mf < 4; mf++)
#pragma unroll
    for (int nf = 0; nf < 2; nf++) {
      ushort4 o4;
      o4.x = f2bf(oacc[mf][nf][0] * inv[nf]);
      o4.y = f2bf(oacc[mf][nf][1] * inv[nf]);
      o4.z = f2bf(oacc[mf][nf][2] * inv[nf]);
      o4.w = f2bf(oacc[mf][nf][3] * inv[nf]);
      *(ushort4*)&o_out[(size_t)(bidx * 1024 + q0w + nf * 16 + lr) * 1024 +
                        h * 64 + mf * 16 + lc * 4] = o4;
    }
}

// ---------- launch ----------
extern "C" void kernel_launch(void* const* d_in, const int* in_sizes, int n_in,
                              void* d_out, int out_size, void* d_ws,
                              size_t ws_size, hipStream_t stream) {
  const float* x      = (const float*)d_in[0];
  const float* ln1_g  = (const float*)d_in[1];
  const float* ln1_b  = (const float*)d_in[2];
  const float* w_qkv  = (const float*)d_in[3];
  const float* b_qkv  = (const float*)d_in[4];
  const float* w_proj = (const float*)d_in[5];
  const float* b_proj = (const float*)d_in[6];
  const float* ln2_g  = (const float*)d_in[7];
  const float* ln2_b  = (const float*)d_in[8];
  const float* w_fc1  = (const float*)d_in[9];
  const float* b_fc1  = (const float*)d_in[10];
  const float* w_fc2  = (const float*)d_in[11];
  const float* b_fc2  = (const float*)d_in[12];
  float* out = (float*)d_out;

  ushort* ws      = (ushort*)d_ws;
  ushort* wt_qkv  = ws;                         // 3072*1024
  ushort* wt_proj = wt_qkv + 3072 * 1024;       // 1024*1024
  ushort* wt_fc1  = wt_proj + 1024 * 1024;      // 4096*1024
  ushort* wt_fc2  = wt_fc1 + 4096 * 1024;       // 1024*4096
  ushort* hbuf    = wt_fc2 + 1024 * 4096;       // 4096*1024
  ushort* qkv     = hbuf + 4096 * 1024;         // 4096*3072
  ushort* obuf    = qkv + 4096 * 3072;          // 4096*1024
  ushort* h3      = qkv;                        // aliases qkv+obuf
  ushort* vtb     = hbuf;                       // vt[64][64][1024]

  transpose_w<<<dim3(96, 32), dim3(32, 8), 0, stream>>>(w_qkv, wt_qkv, 1024, 3072);
  transpose_w<<<dim3(32, 32), dim3(32, 8), 0, stream>>>(w_proj, wt_proj, 1024, 1024);
  transpose_w<<<dim3(128, 32), dim3(32, 8), 0, stream>>>(w_fc1, wt_fc1, 1024, 4096);
  transpose_w<<<dim3(32, 128), dim3(32, 8), 0, stream>>>(w_fc2, wt_fc2, 4096, 1024);

  ln_bf16<<<4096, 256, 0, stream>>>(x, ln1_g, ln1_b, hbuf);
  // QKV: 128^2, grid 24x32=768 (2/CU). XCD rect 12x8, 2 across.
  gemm2ph<128, 128, 4, 0><<<dim3(24, 32), 256, 0, stream>>>(
      hbuf, wt_qkv, b_qkv, nullptr, qkv, 4096, 3072, 1024, 12, 8, 2);
  transpose_v<<<dim3(32, 2, 64), dim3(32, 8), 0, stream>>>(qkv, vtb);
  attn_kernel<<<dim3(8, 64), 256, 0, stream>>>(qkv, vtb, obuf);
  // proj + residual: 128x64, grid 16x32=512 (3/CU). XCD rect 8x8, 2 across.
  gemm2ph<128, 64, 4, 2><<<dim3(16, 32), 256, 0, stream>>>(
      obuf, wt_proj, b_proj, x, out, 4096, 1024, 1024, 8, 8, 2);
  ln_bf16<<<4096, 256, 0, stream>>>(out, ln2_g, ln2_b, hbuf);
  // fc1 + GELU: 128^2, grid 32x32=1024 (2/CU). XCD rect 16x8, 2 across.
  gemm2ph<128, 128, 4, 1><<<dim3(32, 32), 256, 0, stream>>>(
      hbuf, wt_fc1, b_fc1, nullptr, h3, 4096, 4096, 1024, 16, 8, 2);
  // fc2 + residual: 128x64, grid 16x32=512 (3/CU). XCD rect 8x8, 2 across.
  gemm2ph<128, 64, 4, 2><<<dim3(16, 32), 256, 0, stream>>>(
      h3, wt_fc2, b_fc2, out, out, 4096, 1024, 4096, 8, 8, 2);
}